// Round 3
// baseline (560.522 us; speedup 1.0000x reference)
//
#include <hip/hip_runtime.h>
#include <math.h>

#define THRESH    0.5f
#define NEG_POSK  3
#define EPSf      1e-6f
#define CCLS      81
#define TILEA     64

__device__ __forceinline__ float iou_xy(float ax0, float ay0, float ax1, float ay1,
                                        float bx0, float by0, float bx1, float by1) {
    float lx = fmaxf(ax0, bx0), ly = fmaxf(ay0, by0);
    float rx = fminf(ax1, bx1), ry = fminf(ay1, by1);
    float w = fmaxf(rx - lx, 0.f), h = fmaxf(ry - ly, 0.f);
    float inter = w * h;
    float aa = (ax1 - ax0) * (ay1 - ay0);
    float ab = (bx1 - bx0) * (by1 - by0);
    return inter / (aa + ab - inter);
}

// ---------------- kernel A: per-object best anchor (argmax over N, first-max) ----
__global__ void k_object_best(const float* __restrict__ boxes,
                              const float* __restrict__ dboxes,
                              int* __restrict__ defbox_object,
                              int B, int N, int O) {
    int bo = blockIdx.x;
    int b = bo / O, o = bo % O;
    float ax0 = boxes[((size_t)b * O + o) * 4 + 0];
    float ay0 = boxes[((size_t)b * O + o) * 4 + 1];
    float ax1 = boxes[((size_t)b * O + o) * 4 + 2];
    float ay1 = boxes[((size_t)b * O + o) * 4 + 3];
    float best = -1.f; int bi = 0x7FFFFFFF;
    for (int n = threadIdx.x; n < N; n += blockDim.x) {
        float4 d = ((const float4*)dboxes)[n];
        float dx0 = d.x - d.z * 0.5f, dy0 = d.y - d.w * 0.5f;
        float dx1 = d.x + d.z * 0.5f, dy1 = d.y + d.w * 0.5f;
        float iou = iou_xy(ax0, ay0, ax1, ay1, dx0, dy0, dx1, dy1);
        if (iou > best) { best = iou; bi = n; }   // ascending n + strict > = first max
    }
    __shared__ float sv[256];
    __shared__ int   si[256];
    sv[threadIdx.x] = best; si[threadIdx.x] = bi;
    __syncthreads();
    for (int s = 128; s > 0; s >>= 1) {
        if (threadIdx.x < s) {
            float v2 = sv[threadIdx.x + s]; int i2 = si[threadIdx.x + s];
            if (v2 > sv[threadIdx.x] || (v2 == sv[threadIdx.x] && i2 < si[threadIdx.x])) {
                sv[threadIdx.x] = v2; si[threadIdx.x] = i2;
            }
        }
        __syncthreads();
    }
    if (threadIdx.x == 0) defbox_object[bo] = si[0];
}

// ---------------- kernel B: fused match (IoU argmax + force + label + loc) -------
__global__ void k_match(const float* __restrict__ boxes,
                        const float* __restrict__ dboxes,
                        const int* __restrict__ labels,
                        const float* __restrict__ locs_pred,
                        const int* __restrict__ defbox_object,
                        int* __restrict__ t_label,
                        int* __restrict__ n_pos, float* __restrict__ loc_sum,
                        int B, int N, int O) {
    int b = blockIdx.y;
    int n = blockIdx.x * blockDim.x + threadIdx.x;
    __shared__ float sb[64];
    __shared__ int slab[16], sdbo[16];
    if (threadIdx.x < O * 4) sb[threadIdx.x] = boxes[(size_t)b * O * 4 + threadIdx.x];
    if (threadIdx.x >= 64 && threadIdx.x < 64 + O)
        slab[threadIdx.x - 64] = labels[b * O + (threadIdx.x - 64)];
    if (threadIdx.x >= 96 && threadIdx.x < 96 + O)
        sdbo[threadIdx.x - 96] = defbox_object[b * O + (threadIdx.x - 96)];
    __syncthreads();
    float lsum = 0.f; int cnt = 0;
    if (n < N) {
        float4 d = ((const float4*)dboxes)[n];
        float dx0 = d.x - d.z * 0.5f, dy0 = d.y - d.w * 0.5f;
        float dx1 = d.x + d.z * 0.5f, dy1 = d.y + d.w * 0.5f;
        float best = -1.f; int bo = 0;
        for (int o = 0; o < O; ++o) {
            float iou = iou_xy(sb[o*4], sb[o*4+1], sb[o*4+2], sb[o*4+3], dx0, dy0, dx1, dy1);
            if (iou > best) { best = iou; bo = o; }   // first-max (JAX argmax axis=0)
        }
        int sel = bo; bool forced = false;
        for (int o = 0; o < O; ++o)
            if (sdbo[o] == n) { sel = o; forced = true; }   // last-wins scatter
        float iou_eff = forced ? 1.0f : best;
        int lbl = (iou_eff < THRESH) ? 0 : slab[sel];
        size_t idx = (size_t)b * N + n;
        t_label[idx] = lbl;
        if (lbl != 0) {
            cnt = 1;
            float bx0 = sb[sel*4], by0 = sb[sel*4+1], bx1 = sb[sel*4+2], by1 = sb[sel*4+3];
            float bcx = (bx0 + bx1) * 0.5f, bcy = (by0 + by1) * 0.5f;
            float bw = bx1 - bx0, bh = by1 - by0;
            float t0 = (bcx - d.x) / (d.z / 10.0f + EPSf);
            float t1 = (bcy - d.y) / (d.w / 10.0f + EPSf);
            float t2 = logf(bw / d.z + EPSf) * 5.0f;
            float t3 = logf(bh / d.w + EPSf) * 5.0f;
            float4 p = ((const float4*)locs_pred)[idx];
            float dd;
            dd = fabsf(p.x - t0); lsum += (dd < 1.f) ? 0.5f*dd*dd : dd - 0.5f;
            dd = fabsf(p.y - t1); lsum += (dd < 1.f) ? 0.5f*dd*dd : dd - 0.5f;
            dd = fabsf(p.z - t2); lsum += (dd < 1.f) ? 0.5f*dd*dd : dd - 0.5f;
            dd = fabsf(p.w - t3); lsum += (dd < 1.f) ? 0.5f*dd*dd : dd - 0.5f;
        }
    }
    for (int d = 1; d < 64; d <<= 1) {
        lsum += __shfl_xor(lsum, d);
        cnt  += __shfl_xor(cnt, d);
    }
    if ((threadIdx.x & 63) == 0) {
        if (cnt)         atomicAdd(&n_pos[b], cnt);
        if (lsum != 0.f) atomicAdd(loc_sum, lsum);
    }
}

// ---------------- kernel C: per-anchor CE — MLP-staged version (real) ------------
__global__ __launch_bounds__(256) void k_conf(const float* __restrict__ cls,
                                              const int* __restrict__ t_label,
                                              float* __restrict__ vneg,
                                              float* __restrict__ pos_conf,
                                              int B, int N) {
    __shared__ __align__(16) float sm[TILEA * CCLS];   // 20.7 KB of exp(x)
    int b = blockIdx.y;
    int a0 = blockIdx.x * TILEA;
    int valid = min(TILEA, N - a0);
    const float* g = cls + ((size_t)b * N + a0) * CCLS;
    const float4* g4 = (const float4*)g;
    float4* sm4 = (float4*)sm;
    int tid = threadIdx.x;
    if (valid == TILEA) {
        // 1296 float4: 5 per thread + 16 extra. Issue all loads independently
        // (registers) so 5-6 are outstanding per wave, then exp + LDS write.
        float4 r0 = g4[tid];
        float4 r1 = g4[tid + 256];
        float4 r2 = g4[tid + 512];
        float4 r3 = g4[tid + 768];
        float4 r4 = g4[tid + 1024];
        float4 r5;
        bool has5 = tid < 16;
        if (has5) r5 = g4[tid + 1280];
        r0.x=__expf(r0.x); r0.y=__expf(r0.y); r0.z=__expf(r0.z); r0.w=__expf(r0.w);
        r1.x=__expf(r1.x); r1.y=__expf(r1.y); r1.z=__expf(r1.z); r1.w=__expf(r1.w);
        r2.x=__expf(r2.x); r2.y=__expf(r2.y); r2.z=__expf(r2.z); r2.w=__expf(r2.w);
        r3.x=__expf(r3.x); r3.y=__expf(r3.y); r3.z=__expf(r3.z); r3.w=__expf(r3.w);
        r4.x=__expf(r4.x); r4.y=__expf(r4.y); r4.z=__expf(r4.z); r4.w=__expf(r4.w);
        sm4[tid]        = r0;
        sm4[tid + 256]  = r1;
        sm4[tid + 512]  = r2;
        sm4[tid + 768]  = r3;
        sm4[tid + 1024] = r4;
        if (has5) {
            r5.x=__expf(r5.x); r5.y=__expf(r5.y); r5.z=__expf(r5.z); r5.w=__expf(r5.w);
            sm4[tid + 1280] = r5;
        }
    } else {
        int len = valid * CCLS, nvec = len >> 2;
        for (int iv = tid; iv < nvec; iv += 256) {
            float4 v = g4[iv];
            v.x=__expf(v.x); v.y=__expf(v.y); v.z=__expf(v.z); v.w=__expf(v.w);
            sm4[iv] = v;
        }
        for (int i = (nvec << 2) + tid; i < len; i += 256) sm[i] = __expf(g[i]);
    }
    __syncthreads();

    int a = tid >> 2, p = tid & 3;                    // 4 lanes per anchor
    bool active = (a < valid);
    const float* row = &sm[a * CCLS];
    int base = p * 20;
    float s = 0.f;
    #pragma unroll
    for (int i = 0; i < 21; ++i) {
        float e = row[base + i];
        bool use = (i < 20) | (p == 3);               // col 80 counted once
        s += use ? e : 0.f;
    }
    s += __shfl_xor(s, 1);
    s += __shfl_xor(s, 2);
    float contrib = 0.f;
    if (active && p == 0) {
        int ag = a0 + a;
        int lbl = t_label[(size_t)b * N + ag];
        float conf = __logf(s) - __logf(row[lbl]);
        bool pos = (lbl != 0);
        vneg[(size_t)b * N + ag] = pos ? 0.f : conf;
        contrib = pos ? conf : 0.f;
    }
    #pragma unroll
    for (int d = 1; d < 64; d <<= 1) contrib += __shfl_xor(contrib, d);
    if ((tid & 63) == 0 && contrib != 0.f) atomicAdd(pos_conf, contrib);
}

// ---------------- PROBE kA: old rolled staging + LDS + barrier (half grid) -------
__global__ __launch_bounds__(256) void k_probe_stage(const float* __restrict__ cls, int N) {
    __shared__ __align__(16) float sm[TILEA * CCLS];
    int b = blockIdx.y;
    int a0 = blockIdx.x * TILEA;
    int valid = min(TILEA, N - a0);
    int len = valid * CCLS, nvec = len >> 2;
    const float* g = cls + ((size_t)b * N + a0) * CCLS;
    for (int iv = threadIdx.x; iv < nvec; iv += 256) {
        float4 v = ((const float4*)g)[iv];
        v.x=__expf(v.x); v.y=__expf(v.y); v.z=__expf(v.z); v.w=__expf(v.w);
        ((float4*)sm)[iv] = v;
    }
    __syncthreads();
    float s = sm[threadIdx.x] + sm[threadIdx.x + 1024]
            + sm[threadIdx.x + 2048] + sm[threadIdx.x + 4096];
    asm volatile("" :: "v"(s));   // keep LDS round-trip live (rule 17)
}

// ---------------- PROBE kB: rolled loads + exp, registers only (half grid) -------
__global__ __launch_bounds__(256) void k_probe_load(const float* __restrict__ cls, int N) {
    int b = blockIdx.y;
    int a0 = blockIdx.x * TILEA;
    int valid = min(TILEA, N - a0);
    int len = valid * CCLS, nvec = len >> 2;
    const float* g = cls + ((size_t)b * N + a0) * CCLS;
    float s = 0.f;
    for (int iv = threadIdx.x; iv < nvec; iv += 256) {
        float4 v = ((const float4*)g)[iv];
        s += __expf(v.x) + __expf(v.y) + __expf(v.z) + __expf(v.w);
    }
    asm volatile("" :: "v"(s));   // keep loads+exp live
}

// ---------------- kernel D: exact top-k sum of negatives per batch ---------------
__device__ void wave_select(const int* hist, int nbins, int k, int* out_bin, int* out_k) {
    int lane = threadIdx.x & 63;
    int cum = 0;
    for (int c = nbins / 64 - 1; c >= 0; --c) {
        int val = hist[c * 64 + lane];
        int s = val;                           // descending suffix-sum within chunk
        for (int d = 1; d < 64; d <<= 1) {
            int t = __shfl_down(s, d);
            if (lane + d < 64) s += t;
        }
        int total = __shfl(s, 0);
        if (cum + total >= k) {
            unsigned long long mask = __ballot(cum + s >= k);
            int bl = 63 - __builtin_clzll(mask);
            int sB = __shfl(s, bl);
            int vB = __shfl(val, bl);
            if (lane == 0) {
                *out_bin = c * 64 + bl;
                *out_k = k - (cum + sB - vB);
            }
            return;
        }
        cum += total;
    }
    if (lane == 0) { *out_bin = 0; *out_k = 1; }
}

__global__ __launch_bounds__(1024) void k_select(const float* __restrict__ vneg,
                                                 const int* __restrict__ n_pos,
                                                 float* __restrict__ hard_sum,
                                                 int B, int N) {
    int b = blockIdx.x;
    const float* v = vneg + (size_t)b * N;
    __shared__ int hist[2048];
    __shared__ int bcast_bin, bcast_k;
    __shared__ float swv[16];
    __shared__ int swc[16];
    int np = n_pos[b];
    long long kk = (long long)NEG_POSK * np;
    if (kk > N) kk = N;
    int k = (int)kk;
    if (k <= 0) return;
    int tid = threadIdx.x;

    for (int i = tid; i < 2048; i += 1024) hist[i] = 0;
    __syncthreads();
    for (int n = tid; n < N; n += 1024) {
        unsigned u = __float_as_uint(v[n]);
        atomicAdd(&hist[u >> 20], 1);
    }
    __syncthreads();
    if (tid < 64) wave_select(hist, 2048, k, &bcast_bin, &bcast_k);
    __syncthreads();
    int B1 = bcast_bin, k2 = bcast_k;

    for (int i = tid; i < 2048; i += 1024) hist[i] = 0;
    __syncthreads();
    for (int n = tid; n < N; n += 1024) {
        unsigned u = __float_as_uint(v[n]);
        if ((int)(u >> 20) == B1) atomicAdd(&hist[(u >> 9) & 0x7FF], 1);
    }
    __syncthreads();
    if (tid < 64) wave_select(hist, 2048, k2, &bcast_bin, &bcast_k);
    __syncthreads();
    int B2 = bcast_bin, k3 = bcast_k;
    unsigned pre = ((unsigned)B1 << 11) | (unsigned)B2;

    for (int i = tid; i < 512; i += 1024) hist[i] = 0;
    __syncthreads();
    for (int n = tid; n < N; n += 1024) {
        unsigned u = __float_as_uint(v[n]);
        if ((u >> 9) == pre) atomicAdd(&hist[u & 0x1FF], 1);
    }
    __syncthreads();
    if (tid < 64) wave_select(hist, 512, k3, &bcast_bin, &bcast_k);
    __syncthreads();
    unsigned tau_bits = (pre << 9) | (unsigned)bcast_bin;
    float tau = __uint_as_float(tau_bits);

    float ssum = 0.f; int scnt = 0;
    for (int n = tid; n < N; n += 1024) {
        float x = v[n];
        if (x > tau) { ssum += x; scnt++; }
    }
    for (int d = 1; d < 64; d <<= 1) {
        ssum += __shfl_xor(ssum, d);
        scnt += __shfl_xor(scnt, d);
    }
    int w = tid >> 6;
    if ((tid & 63) == 0) { swv[w] = ssum; swc[w] = scnt; }
    __syncthreads();
    if (tid == 0) {
        float S = 0.f; int Ct = 0;
        for (int i = 0; i < 16; ++i) { S += swv[i]; Ct += swc[i]; }
        float hb = S + (float)(k - Ct) * tau;
        atomicAdd(hard_sum, hb);
    }
}

// ---------------- kernel E: finalize ---------------------------------------------
__global__ void k_final(const int* __restrict__ n_pos,
                        const float* __restrict__ loc_sum,
                        const float* __restrict__ pos_conf,
                        const float* __restrict__ hard_sum,
                        float* __restrict__ out, int B) {
    if (threadIdx.x == 0 && blockIdx.x == 0) {
        int tot = 0;
        for (int b = 0; b < B; ++b) tot += n_pos[b];
        float np = (float)tot;
        float loc = *loc_sum / (np * 4.0f);
        float conf = (*hard_sum + *pos_conf) / np;
        out[0] = 0.5f * loc + conf;
    }
}

extern "C" void kernel_launch(void* const* d_in, const int* in_sizes, int n_in,
                              void* d_out, int out_size, void* d_ws, size_t ws_size,
                              hipStream_t stream) {
    const float* locs_pred = (const float*)d_in[0];
    const float* cls_pred  = (const float*)d_in[1];
    const float* boxes     = (const float*)d_in[2];
    const int*   labels    = (const int*)d_in[3];
    const float* dboxes    = (const float*)d_in[4];

    int N = in_sizes[4] / 4;
    int B = in_sizes[0] / (4 * N);
    int O = in_sizes[3] / B;

    size_t BN = (size_t)B * N;
    char* ws = (char*)d_ws;
    int*   n_pos    = (int*)ws;                       // B ints
    float* loc_sum  = (float*)(ws + 128);
    float* pos_conf = (float*)(ws + 132);
    float* hard_sum = (float*)(ws + 136);
    int*   t_label  = (int*)(ws + 256);               // BN i32
    float* vneg     = (float*)(ws + 256 + BN * 4);    // BN f32
    int*   defbox_object = (int*)(ws + 256 + BN * 8); // B*O i32

    hipMemsetAsync(ws, 0, 256, stream);

    k_object_best<<<B * O, 256, 0, stream>>>(boxes, dboxes, defbox_object, B, N, O);
    dim3 gm((N + 255) / 256, B);
    k_match<<<gm, 256, 0, stream>>>(boxes, dboxes, labels, locs_pred, defbox_object,
                                    t_label, n_pos, loc_sum, B, N, O);
    dim3 g5((N + TILEA - 1) / TILEA, B);
    k_conf<<<g5, 256, 0, stream>>>(cls_pred, t_label, vneg, pos_conf, B, N);
    // diagnostic probes on the first half of the anchors (outputs unused)
    dim3 gp(((N / 2) + TILEA - 1) / TILEA, B);
    k_probe_stage<<<gp, 256, 0, stream>>>(cls_pred, N);
    k_probe_load<<<gp, 256, 0, stream>>>(cls_pred, N);
    k_select<<<B, 1024, 0, stream>>>(vneg, n_pos, hard_sum, B, N);
    k_final<<<1, 1, 0, stream>>>(n_pos, loc_sum, pos_conf, hard_sum, (float*)d_out, B);
}

// Round 4
// 458.604 us; speedup vs baseline: 1.2222x; 1.2222x over previous
//
#include <hip/hip_runtime.h>
#include <math.h>

#define THRESH    0.5f
#define NEG_POSK  3
#define EPSf      1e-6f
#define CCLS      81

__device__ __forceinline__ float iou_xy(float ax0, float ay0, float ax1, float ay1,
                                        float bx0, float by0, float bx1, float by1) {
    float lx = fmaxf(ax0, bx0), ly = fmaxf(ay0, by0);
    float rx = fminf(ax1, bx1), ry = fminf(ay1, by1);
    float w = fmaxf(rx - lx, 0.f), h = fmaxf(ry - ly, 0.f);
    float inter = w * h;
    float aa = (ax1 - ax0) * (ay1 - ay0);
    float ab = (bx1 - bx0) * (by1 - by0);
    return inter / (aa + ab - inter);
}

// ---------------- kernel A: per-object best anchor (argmax over N, first-max) ----
__global__ void k_object_best(const float* __restrict__ boxes,
                              const float* __restrict__ dboxes,
                              int* __restrict__ defbox_object,
                              int B, int N, int O) {
    int bo = blockIdx.x;
    int b = bo / O, o = bo % O;
    float ax0 = boxes[((size_t)b * O + o) * 4 + 0];
    float ay0 = boxes[((size_t)b * O + o) * 4 + 1];
    float ax1 = boxes[((size_t)b * O + o) * 4 + 2];
    float ay1 = boxes[((size_t)b * O + o) * 4 + 3];
    float best = -1.f; int bi = 0x7FFFFFFF;
    for (int n = threadIdx.x; n < N; n += blockDim.x) {
        float4 d = ((const float4*)dboxes)[n];
        float dx0 = d.x - d.z * 0.5f, dy0 = d.y - d.w * 0.5f;
        float dx1 = d.x + d.z * 0.5f, dy1 = d.y + d.w * 0.5f;
        float iou = iou_xy(ax0, ay0, ax1, ay1, dx0, dy0, dx1, dy1);
        if (iou > best) { best = iou; bi = n; }   // ascending n + strict > = first max
    }
    __shared__ float sv[256];
    __shared__ int   si[256];
    sv[threadIdx.x] = best; si[threadIdx.x] = bi;
    __syncthreads();
    for (int s = 128; s > 0; s >>= 1) {
        if (threadIdx.x < s) {
            float v2 = sv[threadIdx.x + s]; int i2 = si[threadIdx.x + s];
            if (v2 > sv[threadIdx.x] || (v2 == sv[threadIdx.x] && i2 < si[threadIdx.x])) {
                sv[threadIdx.x] = v2; si[threadIdx.x] = i2;
            }
        }
        __syncthreads();
    }
    if (threadIdx.x == 0) defbox_object[bo] = si[0];
}

// ---------------- kernel B: fused match (IoU argmax + force + label + loc) -------
__global__ void k_match(const float* __restrict__ boxes,
                        const float* __restrict__ dboxes,
                        const int* __restrict__ labels,
                        const float* __restrict__ locs_pred,
                        const int* __restrict__ defbox_object,
                        int* __restrict__ t_label,
                        int* __restrict__ n_pos, float* __restrict__ loc_sum,
                        int B, int N, int O) {
    int b = blockIdx.y;
    int n = blockIdx.x * blockDim.x + threadIdx.x;
    __shared__ float sb[64];
    __shared__ int slab[16], sdbo[16];
    if (threadIdx.x < O * 4) sb[threadIdx.x] = boxes[(size_t)b * O * 4 + threadIdx.x];
    if (threadIdx.x >= 64 && threadIdx.x < 64 + O)
        slab[threadIdx.x - 64] = labels[b * O + (threadIdx.x - 64)];
    if (threadIdx.x >= 96 && threadIdx.x < 96 + O)
        sdbo[threadIdx.x - 96] = defbox_object[b * O + (threadIdx.x - 96)];
    __syncthreads();
    float lsum = 0.f; int cnt = 0;
    if (n < N) {
        float4 d = ((const float4*)dboxes)[n];
        float dx0 = d.x - d.z * 0.5f, dy0 = d.y - d.w * 0.5f;
        float dx1 = d.x + d.z * 0.5f, dy1 = d.y + d.w * 0.5f;
        float best = -1.f; int bo = 0;
        for (int o = 0; o < O; ++o) {
            float iou = iou_xy(sb[o*4], sb[o*4+1], sb[o*4+2], sb[o*4+3], dx0, dy0, dx1, dy1);
            if (iou > best) { best = iou; bo = o; }   // first-max (JAX argmax axis=0)
        }
        int sel = bo; bool forced = false;
        for (int o = 0; o < O; ++o)
            if (sdbo[o] == n) { sel = o; forced = true; }   // last-wins scatter
        float iou_eff = forced ? 1.0f : best;
        int lbl = (iou_eff < THRESH) ? 0 : slab[sel];
        size_t idx = (size_t)b * N + n;
        t_label[idx] = lbl;
        if (lbl != 0) {
            cnt = 1;
            float bx0 = sb[sel*4], by0 = sb[sel*4+1], bx1 = sb[sel*4+2], by1 = sb[sel*4+3];
            float bcx = (bx0 + bx1) * 0.5f, bcy = (by0 + by1) * 0.5f;
            float bw = bx1 - bx0, bh = by1 - by0;
            float t0 = (bcx - d.x) / (d.z / 10.0f + EPSf);
            float t1 = (bcy - d.y) / (d.w / 10.0f + EPSf);
            float t2 = logf(bw / d.z + EPSf) * 5.0f;
            float t3 = logf(bh / d.w + EPSf) * 5.0f;
            float4 p = ((const float4*)locs_pred)[idx];
            float dd;
            dd = fabsf(p.x - t0); lsum += (dd < 1.f) ? 0.5f*dd*dd : dd - 0.5f;
            dd = fabsf(p.y - t1); lsum += (dd < 1.f) ? 0.5f*dd*dd : dd - 0.5f;
            dd = fabsf(p.z - t2); lsum += (dd < 1.f) ? 0.5f*dd*dd : dd - 0.5f;
            dd = fabsf(p.w - t3); lsum += (dd < 1.f) ? 0.5f*dd*dd : dd - 0.5f;
        }
    }
    for (int d = 1; d < 64; d <<= 1) {
        lsum += __shfl_xor(lsum, d);
        cnt  += __shfl_xor(cnt, d);
    }
    if ((threadIdx.x & 63) == 0) {
        if (cnt)         atomicAdd(&n_pos[b], cnt);
        if (lsum != 0.f) atomicAdd(loc_sum, lsum);
    }
}

// ---------------- kernel C: per-anchor CE — wave-per-anchor, no LDS, no barrier --
__global__ __launch_bounds__(256) void k_conf(const float* __restrict__ cls,
                                              const int* __restrict__ t_label,
                                              float* __restrict__ vneg,
                                              float* __restrict__ pos_conf,
                                              int B, int N, int nwaves) {
    int lane = threadIdx.x & 63;
    int w = blockIdx.x * (blockDim.x >> 6) + (threadIdx.x >> 6);
    long long total = (long long)B * N;
    float pc = 0.f;
    long long idx = w;
    if (idx < total) {
        int b = (int)(idx / N);
        int n = (int)(idx - (long long)b * N);
        while (true) {
            const float* row = cls + ((size_t)b * N + n) * CCLS;
            float x1 = row[lane];                          // 64 consecutive floats
            float x2 = (lane < CCLS - 64) ? row[64 + lane] : 0.f;   // 17-lane tail
            float e = __expf(x1) + ((lane < CCLS - 64) ? __expf(x2) : 0.f);
            #pragma unroll
            for (int d = 1; d < 64; d <<= 1) e += __shfl_xor(e, d);
            int lbl = t_label[idx];
            float xa = __shfl(x1, lbl & 63);
            float xb = __shfl(x2, lbl & 63);
            float xl = (lbl < 64) ? xa : xb;
            float conf = __logf(e) - xl;
            bool pos = (lbl != 0);
            if (lane == 0) {
                vneg[idx] = pos ? 0.f : conf;
                if (pos) pc += conf;
            }
            idx += nwaves;
            if (idx >= total) break;
            n += nwaves;
            if (n >= N) { n -= N; b++; }
        }
    }
    if (lane == 0 && pc != 0.f) atomicAdd(pos_conf, pc);
}

// ---------------- kernel D: exact top-k sum of negatives per batch ---------------
__device__ __forceinline__ void hist_add_agg(int* hist, unsigned bin, bool valid) {
    // one LDS atomic per DISTINCT bin per wave (values concentrate into few
    // exponent bins -> plain per-lane atomics serialize ~64x)
    int lane = threadIdx.x & 63;
    unsigned long long remaining = __ballot(valid);
    while (remaining) {
        int leader = __ffsll(remaining) - 1;
        unsigned lbin = __shfl(bin, leader);
        unsigned long long match = __ballot(valid && bin == lbin);
        if (lane == leader) atomicAdd(&hist[lbin], (int)__popcll(match));
        remaining &= ~match;
    }
}

__device__ void wave_select(const int* hist, int nbins, int k, int* out_bin, int* out_k) {
    int lane = threadIdx.x & 63;
    int cum = 0;
    for (int c = nbins / 64 - 1; c >= 0; --c) {
        int val = hist[c * 64 + lane];
        int s = val;                           // descending suffix-sum within chunk
        for (int d = 1; d < 64; d <<= 1) {
            int t = __shfl_down(s, d);
            if (lane + d < 64) s += t;
        }
        int total = __shfl(s, 0);
        if (cum + total >= k) {
            unsigned long long mask = __ballot(cum + s >= k);
            int bl = 63 - __builtin_clzll(mask);
            int sB = __shfl(s, bl);
            int vB = __shfl(val, bl);
            if (lane == 0) {
                *out_bin = c * 64 + bl;
                *out_k = k - (cum + sB - vB);
            }
            return;
        }
        cum += total;
    }
    if (lane == 0) { *out_bin = 0; *out_k = 1; }
}

__global__ __launch_bounds__(1024) void k_select(const float* __restrict__ vneg,
                                                 const int* __restrict__ n_pos,
                                                 float* __restrict__ hard_sum,
                                                 int B, int N) {
    int b = blockIdx.x;
    const float* v = vneg + (size_t)b * N;
    __shared__ int hist[2048];
    __shared__ int bcast_bin, bcast_k;
    __shared__ float swv[16];
    __shared__ int swc[16];
    int np = n_pos[b];
    long long kk = (long long)NEG_POSK * np;
    if (kk > N) kk = N;
    int k = (int)kk;
    if (k <= 0) return;
    int tid = threadIdx.x;
    int Npad = ((N + 1023) / 1024) * 1024;     // uniform trip count for wave ballots

    // level 1: bits 30..20 (v >= 0 -> float bits order-preserving)
    for (int i = tid; i < 2048; i += 1024) hist[i] = 0;
    __syncthreads();
    for (int base = 0; base < Npad; base += 1024) {
        int n = base + tid;
        bool valid = n < N;
        unsigned u = valid ? __float_as_uint(v[n]) : 0u;
        hist_add_agg(hist, u >> 20, valid);
    }
    __syncthreads();
    if (tid < 64) wave_select(hist, 2048, k, &bcast_bin, &bcast_k);
    __syncthreads();
    int B1 = bcast_bin, k2 = bcast_k;

    // level 2: bits 19..9
    for (int i = tid; i < 2048; i += 1024) hist[i] = 0;
    __syncthreads();
    for (int base = 0; base < Npad; base += 1024) {
        int n = base + tid;
        bool valid = n < N;
        unsigned u = valid ? __float_as_uint(v[n]) : 0u;
        hist_add_agg(hist, (u >> 9) & 0x7FF, valid && (int)(u >> 20) == B1);
    }
    __syncthreads();
    if (tid < 64) wave_select(hist, 2048, k2, &bcast_bin, &bcast_k);
    __syncthreads();
    int B2 = bcast_bin, k3 = bcast_k;
    unsigned pre = ((unsigned)B1 << 11) | (unsigned)B2;

    // level 3: bits 8..0
    for (int i = tid; i < 512; i += 1024) hist[i] = 0;
    __syncthreads();
    for (int base = 0; base < Npad; base += 1024) {
        int n = base + tid;
        bool valid = n < N;
        unsigned u = valid ? __float_as_uint(v[n]) : 0u;
        hist_add_agg(hist, u & 0x1FF, valid && (u >> 9) == pre);
    }
    __syncthreads();
    if (tid < 64) wave_select(hist, 512, k3, &bcast_bin, &bcast_k);
    __syncthreads();
    unsigned tau_bits = (pre << 9) | (unsigned)bcast_bin;
    float tau = __uint_as_float(tau_bits);

    // hard_sum_b = sum(v > tau) + (k - count(v > tau)) * tau
    float ssum = 0.f; int scnt = 0;
    for (int n = tid; n < N; n += 1024) {
        float x = v[n];
        if (x > tau) { ssum += x; scnt++; }
    }
    for (int d = 1; d < 64; d <<= 1) {
        ssum += __shfl_xor(ssum, d);
        scnt += __shfl_xor(scnt, d);
    }
    int w = tid >> 6;
    if ((tid & 63) == 0) { swv[w] = ssum; swc[w] = scnt; }
    __syncthreads();
    if (tid == 0) {
        float S = 0.f; int Ct = 0;
        for (int i = 0; i < 16; ++i) { S += swv[i]; Ct += swc[i]; }
        float hb = S + (float)(k - Ct) * tau;
        atomicAdd(hard_sum, hb);
    }
}

// ---------------- kernel E: finalize ---------------------------------------------
__global__ void k_final(const int* __restrict__ n_pos,
                        const float* __restrict__ loc_sum,
                        const float* __restrict__ pos_conf,
                        const float* __restrict__ hard_sum,
                        float* __restrict__ out, int B) {
    if (threadIdx.x == 0 && blockIdx.x == 0) {
        int tot = 0;
        for (int b = 0; b < B; ++b) tot += n_pos[b];
        float np = (float)tot;
        float loc = *loc_sum / (np * 4.0f);
        float conf = (*hard_sum + *pos_conf) / np;
        out[0] = 0.5f * loc + conf;
    }
}

extern "C" void kernel_launch(void* const* d_in, const int* in_sizes, int n_in,
                              void* d_out, int out_size, void* d_ws, size_t ws_size,
                              hipStream_t stream) {
    const float* locs_pred = (const float*)d_in[0];
    const float* cls_pred  = (const float*)d_in[1];
    const float* boxes     = (const float*)d_in[2];
    const int*   labels    = (const int*)d_in[3];
    const float* dboxes    = (const float*)d_in[4];

    int N = in_sizes[4] / 4;
    int B = in_sizes[0] / (4 * N);
    int O = in_sizes[3] / B;

    size_t BN = (size_t)B * N;
    char* ws = (char*)d_ws;
    int*   n_pos    = (int*)ws;                       // B ints
    float* loc_sum  = (float*)(ws + 128);
    float* pos_conf = (float*)(ws + 132);
    float* hard_sum = (float*)(ws + 136);
    int*   t_label  = (int*)(ws + 256);               // BN i32
    float* vneg     = (float*)(ws + 256 + BN * 4);    // BN f32
    int*   defbox_object = (int*)(ws + 256 + BN * 8); // B*O i32

    hipMemsetAsync(ws, 0, 256, stream);

    k_object_best<<<B * O, 256, 0, stream>>>(boxes, dboxes, defbox_object, B, N, O);
    dim3 gm((N + 255) / 256, B);
    k_match<<<gm, 256, 0, stream>>>(boxes, dboxes, labels, locs_pred, defbox_object,
                                    t_label, n_pos, loc_sum, B, N, O);
    int nblocks = 1024, wpb = 256 / 64;
    k_conf<<<nblocks, 256, 0, stream>>>(cls_pred, t_label, vneg, pos_conf,
                                        B, N, nblocks * wpb);
    k_select<<<B, 1024, 0, stream>>>(vneg, n_pos, hard_sum, B, N);
    k_final<<<1, 1, 0, stream>>>(n_pos, loc_sum, pos_conf, hard_sum, (float*)d_out, B);
}

// Round 5
// 405.895 us; speedup vs baseline: 1.3810x; 1.1299x over previous
//
#include <hip/hip_runtime.h>
#include <math.h>

#define THRESH    0.5f
#define NEG_POSK  3
#define EPSf      1e-6f
#define CCLS      81

__device__ __forceinline__ float iou_xy(float ax0, float ay0, float ax1, float ay1,
                                        float bx0, float by0, float bx1, float by1) {
    float lx = fmaxf(ax0, bx0), ly = fmaxf(ay0, by0);
    float rx = fminf(ax1, bx1), ry = fminf(ay1, by1);
    float w = fmaxf(rx - lx, 0.f), h = fmaxf(ry - ly, 0.f);
    float inter = w * h;
    float aa = (ax1 - ax0) * (ay1 - ay0);
    float ab = (bx1 - bx0) * (by1 - by0);
    return inter / (aa + ab - inter);
}

// ---------------- kernel A: per-object best anchor (argmax over N, first-max) ----
__global__ void k_object_best(const float* __restrict__ boxes,
                              const float* __restrict__ dboxes,
                              int* __restrict__ defbox_object,
                              int B, int N, int O) {
    int bo = blockIdx.x;
    int b = bo / O, o = bo % O;
    float ax0 = boxes[((size_t)b * O + o) * 4 + 0];
    float ay0 = boxes[((size_t)b * O + o) * 4 + 1];
    float ax1 = boxes[((size_t)b * O + o) * 4 + 2];
    float ay1 = boxes[((size_t)b * O + o) * 4 + 3];
    float best = -1.f; int bi = 0x7FFFFFFF;
    for (int n = threadIdx.x; n < N; n += blockDim.x) {
        float4 d = ((const float4*)dboxes)[n];
        float dx0 = d.x - d.z * 0.5f, dy0 = d.y - d.w * 0.5f;
        float dx1 = d.x + d.z * 0.5f, dy1 = d.y + d.w * 0.5f;
        float iou = iou_xy(ax0, ay0, ax1, ay1, dx0, dy0, dx1, dy1);
        if (iou > best) { best = iou; bi = n; }   // ascending n + strict > = first max
    }
    __shared__ float sv[256];
    __shared__ int   si[256];
    sv[threadIdx.x] = best; si[threadIdx.x] = bi;
    __syncthreads();
    for (int s = 128; s > 0; s >>= 1) {
        if (threadIdx.x < s) {
            float v2 = sv[threadIdx.x + s]; int i2 = si[threadIdx.x + s];
            if (v2 > sv[threadIdx.x] || (v2 == sv[threadIdx.x] && i2 < si[threadIdx.x])) {
                sv[threadIdx.x] = v2; si[threadIdx.x] = i2;
            }
        }
        __syncthreads();
    }
    if (threadIdx.x == 0) defbox_object[bo] = si[0];
}

// ---------------- kernel B: fused match (IoU argmax + force + label + loc) -------
__global__ void k_match(const float* __restrict__ boxes,
                        const float* __restrict__ dboxes,
                        const int* __restrict__ labels,
                        const float* __restrict__ locs_pred,
                        const int* __restrict__ defbox_object,
                        int* __restrict__ t_label,
                        int* __restrict__ n_pos, float* __restrict__ loc_sum,
                        int B, int N, int O) {
    int b = blockIdx.y;
    int n = blockIdx.x * blockDim.x + threadIdx.x;
    __shared__ float sb[64];
    __shared__ int slab[16], sdbo[16];
    if (threadIdx.x < O * 4) sb[threadIdx.x] = boxes[(size_t)b * O * 4 + threadIdx.x];
    if (threadIdx.x >= 64 && threadIdx.x < 64 + O)
        slab[threadIdx.x - 64] = labels[b * O + (threadIdx.x - 64)];
    if (threadIdx.x >= 96 && threadIdx.x < 96 + O)
        sdbo[threadIdx.x - 96] = defbox_object[b * O + (threadIdx.x - 96)];
    __syncthreads();
    float lsum = 0.f; int cnt = 0;
    if (n < N) {
        float4 d = ((const float4*)dboxes)[n];
        float dx0 = d.x - d.z * 0.5f, dy0 = d.y - d.w * 0.5f;
        float dx1 = d.x + d.z * 0.5f, dy1 = d.y + d.w * 0.5f;
        float best = -1.f; int bo = 0;
        for (int o = 0; o < O; ++o) {
            float iou = iou_xy(sb[o*4], sb[o*4+1], sb[o*4+2], sb[o*4+3], dx0, dy0, dx1, dy1);
            if (iou > best) { best = iou; bo = o; }   // first-max (JAX argmax axis=0)
        }
        int sel = bo; bool forced = false;
        for (int o = 0; o < O; ++o)
            if (sdbo[o] == n) { sel = o; forced = true; }   // last-wins scatter
        float iou_eff = forced ? 1.0f : best;
        int lbl = (iou_eff < THRESH) ? 0 : slab[sel];
        size_t idx = (size_t)b * N + n;
        t_label[idx] = lbl;
        if (lbl != 0) {
            cnt = 1;
            float bx0 = sb[sel*4], by0 = sb[sel*4+1], bx1 = sb[sel*4+2], by1 = sb[sel*4+3];
            float bcx = (bx0 + bx1) * 0.5f, bcy = (by0 + by1) * 0.5f;
            float bw = bx1 - bx0, bh = by1 - by0;
            float t0 = (bcx - d.x) / (d.z / 10.0f + EPSf);
            float t1 = (bcy - d.y) / (d.w / 10.0f + EPSf);
            float t2 = logf(bw / d.z + EPSf) * 5.0f;
            float t3 = logf(bh / d.w + EPSf) * 5.0f;
            float4 p = ((const float4*)locs_pred)[idx];
            float dd;
            dd = fabsf(p.x - t0); lsum += (dd < 1.f) ? 0.5f*dd*dd : dd - 0.5f;
            dd = fabsf(p.y - t1); lsum += (dd < 1.f) ? 0.5f*dd*dd : dd - 0.5f;
            dd = fabsf(p.z - t2); lsum += (dd < 1.f) ? 0.5f*dd*dd : dd - 0.5f;
            dd = fabsf(p.w - t3); lsum += (dd < 1.f) ? 0.5f*dd*dd : dd - 0.5f;
        }
    }
    for (int d = 1; d < 64; d <<= 1) {
        lsum += __shfl_xor(lsum, d);
        cnt  += __shfl_xor(cnt, d);
    }
    if ((threadIdx.x & 63) == 0) {
        if (cnt)         atomicAdd(&n_pos[b], cnt);
        if (lsum != 0.f) atomicAdd(loc_sum, lsum);
    }
}

// ---------------- kernel C: per-anchor CE — thread-per-anchor register gather ----
// No cross-lane ops in the loop: each thread sums exp over its own 81 floats via
// 20 independent float4 loads (+1 scalar). A wave's 64 rows span a contiguous
// 20.7 KB window, so every cache line is fully consumed.
__global__ __launch_bounds__(256) void k_conf(const float* __restrict__ cls,
                                              const int* __restrict__ t_label,
                                              float* __restrict__ vneg,
                                              float* __restrict__ pos_conf,
                                              long long total, int stride) {
    long long i0 = (long long)blockIdx.x * blockDim.x + threadIdx.x;
    float pc = 0.f;
    for (long long idx = i0; idx < total; idx += stride) {
        const float* row = cls + idx * CCLS;
        const float4* row4 = (const float4*)row;
        float4 r0[10], r1[10];
        #pragma unroll
        for (int j = 0; j < 10; ++j) r0[j] = row4[j];
        #pragma unroll
        for (int j = 0; j < 10; ++j) r1[j] = row4[10 + j];
        float x80 = row[80];
        int lbl = t_label[idx];
        float s = 0.f;
        #pragma unroll
        for (int j = 0; j < 10; ++j)
            s += __expf(r0[j].x) + __expf(r0[j].y) + __expf(r0[j].z) + __expf(r0[j].w);
        #pragma unroll
        for (int j = 0; j < 10; ++j)
            s += __expf(r1[j].x) + __expf(r1[j].y) + __expf(r1[j].z) + __expf(r1[j].w);
        s += __expf(x80);
        float xl = row[lbl];                     // L1-hit reload (avoids reg-indexing)
        float conf = __logf(s) - xl;
        bool pos = (lbl != 0);
        vneg[idx] = pos ? 0.f : conf;
        pc += pos ? conf : 0.f;
    }
    #pragma unroll
    for (int d = 1; d < 64; d <<= 1) pc += __shfl_xor(pc, d);
    if ((threadIdx.x & 63) == 0 && pc != 0.f) atomicAdd(pos_conf, pc);
}

// ---------------- kernel D: exact top-k sum of negatives per batch ---------------
__device__ __forceinline__ void hist_add_agg(int* hist, unsigned bin, bool valid) {
    // one LDS atomic per DISTINCT bin per wave (values concentrate into few bins)
    int lane = threadIdx.x & 63;
    unsigned long long remaining = __ballot(valid);
    while (remaining) {
        int leader = __ffsll(remaining) - 1;
        unsigned lbin = __shfl(bin, leader);
        unsigned long long match = __ballot(valid && bin == lbin);
        if (lane == leader) atomicAdd(&hist[lbin], (int)__popcll(match));
        remaining &= ~match;
    }
}

__device__ void wave_select(const int* hist, int nbins, int k, int* out_bin, int* out_k) {
    int lane = threadIdx.x & 63;
    int cum = 0;
    for (int c = nbins / 64 - 1; c >= 0; --c) {
        int val = hist[c * 64 + lane];
        int s = val;                           // descending suffix-sum within chunk
        for (int d = 1; d < 64; d <<= 1) {
            int t = __shfl_down(s, d);
            if (lane + d < 64) s += t;
        }
        int total = __shfl(s, 0);
        if (cum + total >= k) {
            unsigned long long mask = __ballot(cum + s >= k);
            int bl = 63 - __builtin_clzll(mask);
            int sB = __shfl(s, bl);
            int vB = __shfl(val, bl);
            if (lane == 0) {
                *out_bin = c * 64 + bl;
                *out_k = k - (cum + sB - vB);
            }
            return;
        }
        cum += total;
    }
    if (lane == 0) { *out_bin = 0; *out_k = 1; }
}

__global__ __launch_bounds__(1024) void k_select(const float* __restrict__ vneg,
                                                 const int* __restrict__ n_pos,
                                                 float* __restrict__ hard_sum,
                                                 int B, int N) {
    int b = blockIdx.x;
    const float* v = vneg + (size_t)b * N;
    __shared__ int hist[2048];
    __shared__ int bcast_bin, bcast_k;
    __shared__ float swv[16];
    __shared__ int swc[16];
    int np = n_pos[b];
    long long kk = (long long)NEG_POSK * np;
    if (kk > N) kk = N;
    int k = (int)kk;
    if (k <= 0) return;
    int tid = threadIdx.x;
    int Npad = ((N + 1023) / 1024) * 1024;     // uniform trip count for wave ballots

    // level 1: bits 30..20 (v >= 0 -> float bits order-preserving)
    for (int i = tid; i < 2048; i += 1024) hist[i] = 0;
    __syncthreads();
    for (int base = 0; base < Npad; base += 1024) {
        int n = base + tid;
        bool valid = n < N;
        unsigned u = valid ? __float_as_uint(v[n]) : 0u;
        hist_add_agg(hist, u >> 20, valid);
    }
    __syncthreads();
    if (tid < 64) wave_select(hist, 2048, k, &bcast_bin, &bcast_k);
    __syncthreads();
    int B1 = bcast_bin, k2 = bcast_k;

    // level 2: bits 19..9
    for (int i = tid; i < 2048; i += 1024) hist[i] = 0;
    __syncthreads();
    for (int base = 0; base < Npad; base += 1024) {
        int n = base + tid;
        bool valid = n < N;
        unsigned u = valid ? __float_as_uint(v[n]) : 0u;
        hist_add_agg(hist, (u >> 9) & 0x7FF, valid && (int)(u >> 20) == B1);
    }
    __syncthreads();
    if (tid < 64) wave_select(hist, 2048, k2, &bcast_bin, &bcast_k);
    __syncthreads();
    int B2 = bcast_bin, k3 = bcast_k;
    unsigned pre = ((unsigned)B1 << 11) | (unsigned)B2;

    // level 3: bits 8..0
    for (int i = tid; i < 512; i += 1024) hist[i] = 0;
    __syncthreads();
    for (int base = 0; base < Npad; base += 1024) {
        int n = base + tid;
        bool valid = n < N;
        unsigned u = valid ? __float_as_uint(v[n]) : 0u;
        hist_add_agg(hist, u & 0x1FF, valid && (u >> 9) == pre);
    }
    __syncthreads();
    if (tid < 64) wave_select(hist, 512, k3, &bcast_bin, &bcast_k);
    __syncthreads();
    unsigned tau_bits = (pre << 9) | (unsigned)bcast_bin;
    float tau = __uint_as_float(tau_bits);

    // hard_sum_b = sum(v > tau) + (k - count(v > tau)) * tau
    float ssum = 0.f; int scnt = 0;
    for (int n = tid; n < N; n += 1024) {
        float x = v[n];
        if (x > tau) { ssum += x; scnt++; }
    }
    for (int d = 1; d < 64; d <<= 1) {
        ssum += __shfl_xor(ssum, d);
        scnt += __shfl_xor(scnt, d);
    }
    int w = tid >> 6;
    if ((tid & 63) == 0) { swv[w] = ssum; swc[w] = scnt; }
    __syncthreads();
    if (tid == 0) {
        float S = 0.f; int Ct = 0;
        for (int i = 0; i < 16; ++i) { S += swv[i]; Ct += swc[i]; }
        float hb = S + (float)(k - Ct) * tau;
        atomicAdd(hard_sum, hb);
    }
}

// ---------------- kernel E: finalize ---------------------------------------------
__global__ void k_final(const int* __restrict__ n_pos,
                        const float* __restrict__ loc_sum,
                        const float* __restrict__ pos_conf,
                        const float* __restrict__ hard_sum,
                        float* __restrict__ out, int B) {
    if (threadIdx.x == 0 && blockIdx.x == 0) {
        int tot = 0;
        for (int b = 0; b < B; ++b) tot += n_pos[b];
        float np = (float)tot;
        float loc = *loc_sum / (np * 4.0f);
        float conf = (*hard_sum + *pos_conf) / np;
        out[0] = 0.5f * loc + conf;
    }
}

extern "C" void kernel_launch(void* const* d_in, const int* in_sizes, int n_in,
                              void* d_out, int out_size, void* d_ws, size_t ws_size,
                              hipStream_t stream) {
    const float* locs_pred = (const float*)d_in[0];
    const float* cls_pred  = (const float*)d_in[1];
    const float* boxes     = (const float*)d_in[2];
    const int*   labels    = (const int*)d_in[3];
    const float* dboxes    = (const float*)d_in[4];

    int N = in_sizes[4] / 4;
    int B = in_sizes[0] / (4 * N);
    int O = in_sizes[3] / B;

    size_t BN = (size_t)B * N;
    char* ws = (char*)d_ws;
    int*   n_pos    = (int*)ws;                       // B ints
    float* loc_sum  = (float*)(ws + 128);
    float* pos_conf = (float*)(ws + 132);
    float* hard_sum = (float*)(ws + 136);
    int*   t_label  = (int*)(ws + 256);               // BN i32
    float* vneg     = (float*)(ws + 256 + BN * 4);    // BN f32
    int*   defbox_object = (int*)(ws + 256 + BN * 8); // B*O i32

    hipMemsetAsync(ws, 0, 256, stream);

    k_object_best<<<B * O, 256, 0, stream>>>(boxes, dboxes, defbox_object, B, N, O);
    dim3 gm((N + 255) / 256, B);
    k_match<<<gm, 256, 0, stream>>>(boxes, dboxes, labels, locs_pred, defbox_object,
                                    t_label, n_pos, loc_sum, B, N, O);
    long long total = (long long)B * N;
    int nblocks = 2048;
    k_conf<<<nblocks, 256, 0, stream>>>(cls_pred, t_label, vneg, pos_conf,
                                        total, nblocks * 256);
    k_select<<<B, 1024, 0, stream>>>(vneg, n_pos, hard_sum, B, N);
    k_final<<<1, 1, 0, stream>>>(n_pos, loc_sum, pos_conf, hard_sum, (float*)d_out, B);
}

// Round 6
// 297.366 us; speedup vs baseline: 1.8850x; 1.3650x over previous
//
#include <hip/hip_runtime.h>
#include <math.h>

#define THRESH    0.5f
#define NEG_POSK  3
#define EPSf      1e-6f
#define CCLS      81
#define CHUNKS    16

__device__ __forceinline__ float iou_xy(float ax0, float ay0, float ax1, float ay1,
                                        float bx0, float by0, float bx1, float by1) {
    float lx = fmaxf(ax0, bx0), ly = fmaxf(ay0, by0);
    float rx = fminf(ax1, bx1), ry = fminf(ay1, by1);
    float w = fmaxf(rx - lx, 0.f), h = fmaxf(ry - ly, 0.f);
    float inter = w * h;
    float aa = (ax1 - ax0) * (ay1 - ay0);
    float ab = (bx1 - bx0) * (by1 - by0);
    return inter / (aa + ab - inter);
}

// ---------- kernel 1: per-object best-anchor PARTIAL argmax (16 chunks) ----------
__global__ __launch_bounds__(256) void k_obj_part(const float* __restrict__ boxes,
                                                  const float* __restrict__ dboxes,
                                                  float* __restrict__ part_iou,
                                                  int* __restrict__ part_idx,
                                                  int N, int O) {
    int bo = blockIdx.x;                 // b*O + o  (block-uniform -> scalar loads)
    int c  = blockIdx.y;
    const float* bb = boxes + (size_t)bo * 4;
    float ax0 = bb[0], ay0 = bb[1], ax1 = bb[2], ay1 = bb[3];
    int chunk = (N + CHUNKS - 1) / CHUNKS;
    int n0 = c * chunk;
    int n1 = min(n0 + chunk, N);
    float best = -1.f; int bi = 0x7FFFFFFF;
    for (int n = n0 + threadIdx.x; n < n1; n += 256) {
        float4 d = ((const float4*)dboxes)[n];
        float dx0 = d.x - d.z * 0.5f, dy0 = d.y - d.w * 0.5f;
        float dx1 = d.x + d.z * 0.5f, dy1 = d.y + d.w * 0.5f;
        float iou = iou_xy(ax0, ay0, ax1, ay1, dx0, dy0, dx1, dy1);
        if (iou > best) { best = iou; bi = n; }   // ascending n + strict > = first max
    }
    #pragma unroll
    for (int dd = 1; dd < 64; dd <<= 1) {
        float v2 = __shfl_xor(best, dd); int i2 = __shfl_xor(bi, dd);
        if (v2 > best || (v2 == best && i2 < bi)) { best = v2; bi = i2; }
    }
    __shared__ float sv[4]; __shared__ int si[4];
    int w = threadIdx.x >> 6;
    if ((threadIdx.x & 63) == 0) { sv[w] = best; si[w] = bi; }
    __syncthreads();
    if (threadIdx.x == 0) {
        #pragma unroll
        for (int i = 1; i < 4; ++i)
            if (sv[i] > best || (sv[i] == best && si[i] < bi)) { best = sv[i]; bi = si[i]; }
        part_iou[(size_t)bo * CHUNKS + c] = best;
        part_idx[(size_t)bo * CHUNKS + c] = bi;
    }
}

// ---------- kernel 2: reduce the 16 partials per (b,o) ---------------------------
__global__ void k_obj_reduce(const float* __restrict__ part_iou,
                             const int* __restrict__ part_idx,
                             int* __restrict__ defbox_object, int BO) {
    int bo = blockIdx.x * blockDim.x + threadIdx.x;
    if (bo >= BO) return;
    float best = -1.f; int bi = 0x7FFFFFFF;
    #pragma unroll
    for (int c = 0; c < CHUNKS; ++c) {
        float v = part_iou[(size_t)bo * CHUNKS + c];
        int  i = part_idx[(size_t)bo * CHUNKS + c];
        if (v > best || (v == best && i < bi)) { best = v; bi = i; }
    }
    defbox_object[bo] = bi;
}

// ---------- kernel 3: FUSED match + label + smooth-L1 + CE -----------------------
// b = blockIdx.y (uniform -> boxes/dbo scalarize to SGPRs, loop-invariant);
// O template const -> IoU/scan loops fully unrolled; no LDS, no barriers.
// CE row loads issued first so match math hides under them.
template<int OT>
__global__ __launch_bounds__(256)
void k_fused(const float* __restrict__ locs_pred,
             const float* __restrict__ cls,
             const float* __restrict__ boxes,
             const int* __restrict__ labels,
             const float* __restrict__ dboxes,
             const int* __restrict__ dbo_g,
             float* __restrict__ vneg,
             int* __restrict__ n_pos,
             float* __restrict__ loc_sum,
             float* __restrict__ pos_conf,
             int N, int O_rt) {
    const int O = OT ? OT : O_rt;
    const int b = blockIdx.y;
    const float* __restrict__ bb = boxes + (size_t)b * O * 4;
    const int* __restrict__ lb   = labels + (size_t)b * O;
    const int* __restrict__ dbo  = dbo_g + (size_t)b * O;
    float pc = 0.f, ls = 0.f; int cnt = 0;
    const int stride = gridDim.x * blockDim.x;
    for (int n = blockIdx.x * blockDim.x + threadIdx.x; n < N; n += stride) {
        const size_t idx = (size_t)b * N + n;
        const float* __restrict__ row = cls + idx * CCLS;
        const float4* __restrict__ row4 = (const float4*)row;
        float4 r0[10], r1[10];
        #pragma unroll
        for (int j = 0; j < 10; ++j) r0[j] = row4[j];
        #pragma unroll
        for (int j = 0; j < 10; ++j) r1[j] = row4[10 + j];
        float x80 = row[80];
        float4 d = ((const float4*)dboxes)[n];
        float dx0 = d.x - d.z * 0.5f, dy0 = d.y - d.w * 0.5f;
        float dx1 = d.x + d.z * 0.5f, dy1 = d.y + d.w * 0.5f;
        float best = -1.f; int sel = 0;
        #pragma unroll
        for (int o = 0; o < O; ++o) {
            float iou = iou_xy(bb[o*4], bb[o*4+1], bb[o*4+2], bb[o*4+3],
                               dx0, dy0, dx1, dy1);
            if (iou > best) { best = iou; sel = o; }   // first-max (JAX argmax axis=0)
        }
        bool forced = false;
        #pragma unroll
        for (int o = 0; o < O; ++o)
            if (dbo[o] == n) { sel = o; forced = true; }   // last-wins scatter
        float iou_eff = forced ? 1.0f : best;
        int lbl = (iou_eff < THRESH) ? 0 : lb[sel];
        float s = 0.f;
        #pragma unroll
        for (int j = 0; j < 10; ++j)
            s += __expf(r0[j].x) + __expf(r0[j].y) + __expf(r0[j].z) + __expf(r0[j].w);
        #pragma unroll
        for (int j = 0; j < 10; ++j)
            s += __expf(r1[j].x) + __expf(r1[j].y) + __expf(r1[j].z) + __expf(r1[j].w);
        s += __expf(x80);
        float conf = __logf(s) - row[lbl];           // L1-hit reload of x[lbl]
        bool pos = (lbl != 0);
        vneg[idx] = pos ? 0.f : conf;
        if (pos) {
            pc += conf; cnt++;
            float bx0 = bb[sel*4], by0 = bb[sel*4+1], bx1 = bb[sel*4+2], by1 = bb[sel*4+3];
            float bcx = (bx0 + bx1) * 0.5f, bcy = (by0 + by1) * 0.5f;
            float bw = bx1 - bx0, bh = by1 - by0;
            float t0 = (bcx - d.x) / (d.z / 10.0f + EPSf);
            float t1 = (bcy - d.y) / (d.w / 10.0f + EPSf);
            float t2 = __logf(bw / d.z + EPSf) * 5.0f;
            float t3 = __logf(bh / d.w + EPSf) * 5.0f;
            float4 p = ((const float4*)locs_pred)[idx];
            float dd;
            dd = fabsf(p.x - t0); ls += (dd < 1.f) ? 0.5f*dd*dd : dd - 0.5f;
            dd = fabsf(p.y - t1); ls += (dd < 1.f) ? 0.5f*dd*dd : dd - 0.5f;
            dd = fabsf(p.z - t2); ls += (dd < 1.f) ? 0.5f*dd*dd : dd - 0.5f;
            dd = fabsf(p.w - t3); ls += (dd < 1.f) ? 0.5f*dd*dd : dd - 0.5f;
        }
    }
    #pragma unroll
    for (int dd = 1; dd < 64; dd <<= 1) {
        pc  += __shfl_xor(pc, dd);
        ls  += __shfl_xor(ls, dd);
        cnt += __shfl_xor(cnt, dd);
    }
    if ((threadIdx.x & 63) == 0 && cnt) {
        atomicAdd(&n_pos[b], cnt);
        atomicAdd(loc_sum, ls);
        atomicAdd(pos_conf, pc);
    }
}

// ---------- kernel 4: exact top-k sum of negatives per batch ---------------------
__device__ __forceinline__ void hist_add_agg(int* hist, unsigned bin, bool valid) {
    int lane = threadIdx.x & 63;
    unsigned long long remaining = __ballot(valid);
    while (remaining) {
        int leader = __ffsll(remaining) - 1;
        unsigned lbin = __shfl(bin, leader);
        unsigned long long match = __ballot(valid && bin == lbin);
        if (lane == leader) atomicAdd(&hist[lbin], (int)__popcll(match));
        remaining &= ~match;
    }
}

__device__ void wave_select(const int* hist, int nbins, int k, int* out_bin, int* out_k) {
    int lane = threadIdx.x & 63;
    int cum = 0;
    for (int c = nbins / 64 - 1; c >= 0; --c) {
        int val = hist[c * 64 + lane];
        int s = val;
        for (int d = 1; d < 64; d <<= 1) {
            int t = __shfl_down(s, d);
            if (lane + d < 64) s += t;
        }
        int total = __shfl(s, 0);
        if (cum + total >= k) {
            unsigned long long mask = __ballot(cum + s >= k);
            int bl = 63 - __builtin_clzll(mask);
            int sB = __shfl(s, bl);
            int vB = __shfl(val, bl);
            if (lane == 0) {
                *out_bin = c * 64 + bl;
                *out_k = k - (cum + sB - vB);
            }
            return;
        }
        cum += total;
    }
    if (lane == 0) { *out_bin = 0; *out_k = 1; }
}

__global__ __launch_bounds__(1024) void k_select(const float* __restrict__ vneg,
                                                 const int* __restrict__ n_pos,
                                                 float* __restrict__ hard_sum,
                                                 int B, int N) {
    int b = blockIdx.x;
    const float* v = vneg + (size_t)b * N;
    __shared__ int hist[2048];
    __shared__ int bcast_bin, bcast_k;
    __shared__ float swv[16];
    __shared__ int swc[16];
    int np = n_pos[b];
    long long kk = (long long)NEG_POSK * np;
    if (kk > N) kk = N;
    int k = (int)kk;
    if (k <= 0) return;
    int tid = threadIdx.x;
    int Npad = ((N + 1023) / 1024) * 1024;

    for (int i = tid; i < 2048; i += 1024) hist[i] = 0;
    __syncthreads();
    for (int base = 0; base < Npad; base += 1024) {
        int n = base + tid;
        bool valid = n < N;
        unsigned u = valid ? __float_as_uint(v[n]) : 0u;
        hist_add_agg(hist, u >> 20, valid);
    }
    __syncthreads();
    if (tid < 64) wave_select(hist, 2048, k, &bcast_bin, &bcast_k);
    __syncthreads();
    int B1 = bcast_bin, k2 = bcast_k;

    for (int i = tid; i < 2048; i += 1024) hist[i] = 0;
    __syncthreads();
    for (int base = 0; base < Npad; base += 1024) {
        int n = base + tid;
        bool valid = n < N;
        unsigned u = valid ? __float_as_uint(v[n]) : 0u;
        hist_add_agg(hist, (u >> 9) & 0x7FF, valid && (int)(u >> 20) == B1);
    }
    __syncthreads();
    if (tid < 64) wave_select(hist, 2048, k2, &bcast_bin, &bcast_k);
    __syncthreads();
    int B2 = bcast_bin, k3 = bcast_k;
    unsigned pre = ((unsigned)B1 << 11) | (unsigned)B2;

    for (int i = tid; i < 512; i += 1024) hist[i] = 0;
    __syncthreads();
    for (int base = 0; base < Npad; base += 1024) {
        int n = base + tid;
        bool valid = n < N;
        unsigned u = valid ? __float_as_uint(v[n]) : 0u;
        hist_add_agg(hist, u & 0x1FF, valid && (u >> 9) == pre);
    }
    __syncthreads();
    if (tid < 64) wave_select(hist, 512, k3, &bcast_bin, &bcast_k);
    __syncthreads();
    unsigned tau_bits = (pre << 9) | (unsigned)bcast_bin;
    float tau = __uint_as_float(tau_bits);

    float ssum = 0.f; int scnt = 0;
    for (int n = tid; n < N; n += 1024) {
        float x = v[n];
        if (x > tau) { ssum += x; scnt++; }
    }
    for (int d = 1; d < 64; d <<= 1) {
        ssum += __shfl_xor(ssum, d);
        scnt += __shfl_xor(scnt, d);
    }
    int w = tid >> 6;
    if ((tid & 63) == 0) { swv[w] = ssum; swc[w] = scnt; }
    __syncthreads();
    if (tid == 0) {
        float S = 0.f; int Ct = 0;
        for (int i = 0; i < 16; ++i) { S += swv[i]; Ct += swc[i]; }
        float hb = S + (float)(k - Ct) * tau;
        atomicAdd(hard_sum, hb);
    }
}

// ---------- kernel 5: finalize ---------------------------------------------------
__global__ void k_final(const int* __restrict__ n_pos,
                        const float* __restrict__ loc_sum,
                        const float* __restrict__ pos_conf,
                        const float* __restrict__ hard_sum,
                        float* __restrict__ out, int B) {
    if (threadIdx.x == 0 && blockIdx.x == 0) {
        int tot = 0;
        for (int b = 0; b < B; ++b) tot += n_pos[b];
        float np = (float)tot;
        float loc = *loc_sum / (np * 4.0f);
        float conf = (*hard_sum + *pos_conf) / np;
        out[0] = 0.5f * loc + conf;
    }
}

extern "C" void kernel_launch(void* const* d_in, const int* in_sizes, int n_in,
                              void* d_out, int out_size, void* d_ws, size_t ws_size,
                              hipStream_t stream) {
    const float* locs_pred = (const float*)d_in[0];
    const float* cls_pred  = (const float*)d_in[1];
    const float* boxes     = (const float*)d_in[2];
    const int*   labels    = (const int*)d_in[3];
    const float* dboxes    = (const float*)d_in[4];

    int N = in_sizes[4] / 4;
    int B = in_sizes[0] / (4 * N);
    int O = in_sizes[3] / B;
    int BO = B * O;

    size_t BN = (size_t)B * N;
    char* ws = (char*)d_ws;
    int*   n_pos    = (int*)ws;                         // B ints
    float* loc_sum  = (float*)(ws + 128);
    float* pos_conf = (float*)(ws + 132);
    float* hard_sum = (float*)(ws + 136);
    float* vneg     = (float*)(ws + 256);               // BN f32
    int*   defbox_object = (int*)(ws + 256 + BN * 4);   // BO i32
    float* part_iou = (float*)(ws + 256 + BN * 4 + (size_t)BO * 4);
    int*   part_idx = (int*)(ws + 256 + BN * 4 + (size_t)BO * 4 + (size_t)BO * CHUNKS * 4);

    hipMemsetAsync(ws, 0, 256, stream);

    dim3 gop(BO, CHUNKS);
    k_obj_part<<<gop, 256, 0, stream>>>(boxes, dboxes, part_iou, part_idx, N, O);
    k_obj_reduce<<<(BO + 255) / 256, 256, 0, stream>>>(part_iou, part_idx,
                                                       defbox_object, BO);
    dim3 gf(48, B);
    if (O == 16)
        k_fused<16><<<gf, 256, 0, stream>>>(locs_pred, cls_pred, boxes, labels, dboxes,
                                            defbox_object, vneg, n_pos, loc_sum,
                                            pos_conf, N, O);
    else
        k_fused<0><<<gf, 256, 0, stream>>>(locs_pred, cls_pred, boxes, labels, dboxes,
                                           defbox_object, vneg, n_pos, loc_sum,
                                           pos_conf, N, O);
    k_select<<<B, 1024, 0, stream>>>(vneg, n_pos, hard_sum, B, N);
    k_final<<<1, 1, 0, stream>>>(n_pos, loc_sum, pos_conf, hard_sum, (float*)d_out, B);
}